// Round 24
// baseline (374.113 us; speedup 1.0000x reference)
//
#include <hip/hip_runtime.h>
#include <hip/hip_bf16.h>
#include <math.h>

// Problem constants
#define BB 2
#define SS 2048
#define DD 2048
#define HH 16
#define CONVC 6144
#define MM (BB*SS)   // 4096 tokens

// chunked delta-rule constants
#define CH 64        // chunk length
#define NCH 32       // chunks per sequence
#define CD_KTS 0
#define CD_TV  16384
#define CD_TP  32768
#define CD_AQ  40960
#define CD_PV  49152
#define CD_PC  49408
#define CD_STRIDE 49664

typedef __bf16 bf16_t;
typedef __bf16 bf16x8 __attribute__((ext_vector_type(8)));
typedef __bf16 bf16x4 __attribute__((ext_vector_type(4)));
typedef __bf16 bf16x2 __attribute__((ext_vector_type(2)));
typedef float  f32x4  __attribute__((ext_vector_type(4)));

#define GLOBAL_AS __attribute__((address_space(1)))
#define LDS_AS    __attribute__((address_space(3)))

#define MFMA16(a,b,c) __builtin_amdgcn_mfma_f32_16x16x32_bf16((a),(b),(c),0,0,0)

// raw LDS-only barrier: no vmcnt drain (prefetch loads stay in flight)
#define BAR_LDS() do {                                                         \
  __builtin_amdgcn_sched_barrier(0);                                           \
  asm volatile("s_waitcnt lgkmcnt(0)" ::: "memory");                           \
  __builtin_amdgcn_sched_barrier(0);                                           \
  __builtin_amdgcn_s_barrier();                                                \
  __builtin_amdgcn_sched_barrier(0);                                           \
} while (0)

// ---------------------------------------------------------------------------
// cast_all: one grid-stride kernel for every f32->bf16 cast.
// ---------------------------------------------------------------------------
__global__ __launch_bounds__(256) void cast_all_kernel(
    const float* __restrict__ hs, const float* __restrict__ amask,
    const float* __restrict__ Wqkv, const float* __restrict__ Wz,
    const float* __restrict__ Wb, const float* __restrict__ Wa,
    const float* __restrict__ Wout,
    bf16_t* __restrict__ x_bf, bf16_t* __restrict__ wB,
    bf16_t* __restrict__ wba, bf16_t* __restrict__ woutb)
{
  const long N0 = (long)MM*DD/4;            // x
  const long N1 = N0 + (long)CONVC*DD/4;    // Wqkv
  const long N2 = N1 + (long)DD*DD/4;       // Wz
  const long N3 = N2 + 16*DD/4;             // Wb
  const long N4 = N3 + 16*DD/4;             // Wa
  const long N5 = N4 + (long)DD*DD/4;       // Wout
  for (long i = (long)blockIdx.x*256 + threadIdx.x; i < N5; i += (long)gridDim.x*256) {
    const float* src; bf16_t* dst; float m = 1.f;
    if (i < N0)      { long j=i;    src = hs   + j*4; dst = x_bf + j*4; m = amask[(j*4)/DD]; }
    else if (i < N1) { long j=i-N0; src = Wqkv + j*4; dst = wB + j*4; }
    else if (i < N2) { long j=i-N1; src = Wz   + j*4; dst = wB + (size_t)CONVC*DD + j*4; }
    else if (i < N3) { long j=i-N2; src = Wb   + j*4; dst = wba + j*4; }
    else if (i < N4) { long j=i-N3; src = Wa   + j*4; dst = wba + 16*DD + j*4; }
    else             { long j=i-N4; src = Wout + j*4; dst = woutb + j*4; }
    float4 v = *(const float4*)src;
    bf16x4 o4;
    o4[0]=(bf16_t)(v.x*m); o4[1]=(bf16_t)(v.y*m);
    o4[2]=(bf16_t)(v.z*m); o4[3]=(bf16_t)(v.w*m);
    *(bf16x4*)dst = o4;
  }
}

// ---------------------------------------------------------------------------
// betag3: pb/pa via 1-wave MFMA (16 tokens x 32 outputs, K=2048)
// ---------------------------------------------------------------------------
__global__ __launch_bounds__(64) void betag3_kernel(
    const bf16_t* __restrict__ xbf, const bf16_t* __restrict__ wba,
    const float* __restrict__ dtb, const float* __restrict__ Alog,
    float2* __restrict__ gb_t)
{
  const int blk = blockIdx.x;
  const int lane = threadIdx.x;
  const int fr = lane & 15, fq = lane >> 4;
  const long tok0 = (long)blk*16;

  f32x4 acc0 = {0,0,0,0}, acc1 = {0,0,0,0};
  const bf16_t* ar = xbf + (tok0 + fr)*DD + fq*8;
  const bf16_t* b0 = wba + fr*DD + fq*8;
  const bf16_t* b1 = wba + (16+fr)*DD + fq*8;
  #pragma unroll 4
  for (int ks=0; ks<64; ++ks) {
    bf16x8 a8 = *(const bf16x8*)(ar + ks*32);
    bf16x8 p8 = *(const bf16x8*)(b0 + ks*32);
    bf16x8 q8 = *(const bf16x8*)(b1 + ks*32);
    acc0 = MFMA16(a8, p8, acc0);
    acc1 = MFMA16(a8, q8, acc1);
  }
  const int h = fr;
  float eA = expf(Alog[h]);
  float db = dtb[h];
  #pragma unroll
  for (int r=0;r<4;r++) {
    long tok = tok0 + fq*4 + r;
    int b = (int)(tok >> 11), s = (int)(tok & (SS-1));
    float beta = 1.f/(1.f+expf(-acc0[r]));
    float tt2 = acc1[r] + db;
    float sp = (tt2 > 20.f) ? tt2 : log1pf(expf(tt2));
    float g  = -eA * sp;
    gb_t[((long)b*HH + h)*SS + s] = make_float2(g, beta);
  }
}

// ---------------------------------------------------------------------------
// Fused 256x256 bf16 GEMM over B = [Wqkv; Wz] (8192 rows, 32 N-tiles).
// 512 blocks = EXACTLY 2 rounds at 1 block/CU.
// ---------------------------------------------------------------------------
__global__ __launch_bounds__(512) void gemm_fused(
    const bf16_t* __restrict__ A, const bf16_t* __restrict__ Bm,
    bf16_t* __restrict__ Cmix, bf16_t* __restrict__ Cz, int K, int nbn)
{
  extern __shared__ char gsm[];   // A: buf0@0, buf1@32768; B: +65536
  const int t    = threadIdx.x;
  const int lane = t & 63;
  const int wid  = t >> 6;
  const int wm   = wid >> 2, wn = wid & 3;
  const int fr   = lane & 15, fq = lane >> 4;

  const int nwg = gridDim.x;
  const int wg  = ((int)blockIdx.x & 7)*(nwg >> 3) + ((int)blockIdx.x >> 3);
  const int grp = wg / (nbn*4);
  const int rem = wg - grp*(nbn*4);
  const long bm = grp*4 + (rem & 3);
  const long bn = rem >> 2;

  int rowS[2], colS[2];
  #pragma unroll
  for (int i=0;i<2;i++) {
    int L  = (i*512 + t)*16;
    int Ls = L ^ (((L>>9)&1)<<5);
    rowS[i] = (Ls>>10)*16 + ((Ls&1023)>>6);
    colS[i] = (Ls&63)>>1;
  }
  const bf16_t* Ab = A  + (bm*256)*(long)K;
  const bf16_t* Bb = Bm + (bn*256)*(long)K;

  f32x4 acc[8][4];
  #pragma unroll
  for (int i=0;i<8;i++)
    #pragma unroll
    for (int j=0;j<4;j++) acc[i][j] = (f32x4){0.f,0.f,0.f,0.f};

  const int aoff = fr*64 + ((fq*16) ^ ((fr&8)<<2));

  auto stage = [&](int buf, int oper, int kh, int kt) {
    const bf16_t* srcb = oper ? Bb : Ab;
    char* dst0 = gsm + oper*65536 + buf*32768 + kh*16384 + t*16;
    #pragma unroll
    for (int i=0;i<2;i++) {
      const bf16_t* src = srcb + (long)rowS[i]*K + kt*64 + kh*32 + colS[i];
      __builtin_amdgcn_global_load_lds((const GLOBAL_AS void*)src,
          (LDS_AS void*)(dst0 + i*8192), 16, 0, 0);
    }
  };

  stage(0,0,0,0); stage(0,1,0,0); stage(0,0,1,0); stage(0,1,1,0);
  asm volatile("s_waitcnt vmcnt(4)" ::: "memory");
  __builtin_amdgcn_s_barrier();

  bf16x8 bfr[4];
  int cb = 0;
  const int KT = K >> 6;
  for (int kt=0; kt<KT; ++kt) {
    const int ktn = (kt+1 < KT) ? kt+1 : kt;
    const char* abuf = gsm + cb*32768;
    const char* bbuf = gsm + 65536 + cb*32768;

    #pragma unroll
    for (int ph=0; ph<4; ph++) {
      const int kh = ph >> 1, mh = ph & 1;
      bf16x8 af[4];
      #pragma unroll
      for (int j=0;j<4;j++)
        af[j] = *(const bf16x8*)(abuf + kh*16384 + (wm*8 + mh*4 + j)*1024 + aoff);
      if (mh == 0) {
        #pragma unroll
        for (int n=0;n<4;n++)
          bfr[n] = *(const bf16x8*)(bbuf + kh*16384 + (wn*4+n)*1024 + aoff);
      }
      stage(cb^1, mh, kh, ktn);
      if (mh == 1) {
        __builtin_amdgcn_sched_barrier(0);
        asm volatile("s_waitcnt vmcnt(4)" ::: "memory");
      }
      __builtin_amdgcn_sched_barrier(0);
      __builtin_amdgcn_s_barrier();
      asm volatile("s_waitcnt lgkmcnt(0)" ::: "memory");
      __builtin_amdgcn_sched_barrier(0);
      __builtin_amdgcn_s_setprio(1);
      #pragma unroll
      for (int j=0;j<4;j++)
        #pragma unroll
        for (int n=0;n<4;n++)
          acc[mh*4+j][n] = MFMA16(af[j], bfr[n], acc[mh*4+j][n]);
      __builtin_amdgcn_s_setprio(0);
    }
    cb ^= 1;
  }
  __syncthreads();

  bf16_t* Co;
  long No, colb;
  if (bn < 24) { Co = Cmix; No = CONVC; colb = bn*256; }
  else         { Co = Cz;   No = DD;    colb = (bn-24)*256; }

  #pragma unroll
  for (int mi=0;mi<8;mi++) {
    #pragma unroll
    for (int ni=0;ni<4;ni++) {
      long row = bm*256 + wm*128 + mi*16 + fq*4;
      long col = colb + wn*64 + ni*16 + fr;
      #pragma unroll
      for (int r=0;r<4;r++)
        Co[(row+r)*No + col] = (bf16_t)acc[mi][ni][r];
    }
  }
}

// ---------------------------------------------------------------------------
// 256x128 bf16 GEMM (out-GEMM: 256 blocks = one full round)
// ---------------------------------------------------------------------------
template<bool OUT_BF16>
__global__ __launch_bounds__(512) void gemm256(
    const bf16_t* __restrict__ A, const bf16_t* __restrict__ Bm,
    void* __restrict__ Cp, int M, int N, int K, int nbn)
{
  extern __shared__ char gsm[];
  const int t    = threadIdx.x;
  const int lane = t & 63;
  const int wid  = t >> 6;
  const int wm   = wid >> 2, wn = wid & 3;
  const int fr   = lane & 15, fq = lane >> 4;

  const int nwg = gridDim.x;
  const int wg  = ((int)blockIdx.x & 7)*(nwg >> 3) + ((int)blockIdx.x >> 3);
  const int grp = wg / (nbn*4);
  const int rem = wg - grp*(nbn*4);
  const long bm = grp*4 + (rem & 3);
  const long bn = rem >> 2;

  int rowS[2], colS[2];
  #pragma unroll
  for (int i=0;i<2;i++) {
    int L  = (i*512 + t)*16;
    int Ls = L ^ (((L>>9)&1)<<5);
    rowS[i] = (Ls>>10)*16 + ((Ls&1023)>>6);
    colS[i] = (Ls&63)>>1;
  }
  const bf16_t* Ab = A  + (bm*256)*(long)K;
  const bf16_t* Bb = Bm + (bn*128)*(long)K;

  f32x4 acc[8][2];
  #pragma unroll
  for (int i=0;i<8;i++) { acc[i][0] = (f32x4){0,0,0,0}; acc[i][1] = (f32x4){0,0,0,0}; }

  const int aoff = fr*64 + ((fq*16) ^ ((fr&8)<<2));

  auto stageA = [&](int buf, int kh, int kt) {
    char* dst0 = gsm + buf*32768 + kh*16384 + t*16;
    #pragma unroll
    for (int i=0;i<2;i++) {
      const bf16_t* src = Ab + (long)rowS[i]*K + kt*64 + kh*32 + colS[i];
      __builtin_amdgcn_global_load_lds((const GLOBAL_AS void*)src,
          (LDS_AS void*)(dst0 + i*8192), 16, 0, 0);
    }
  };
  auto stageB = [&](int buf, int kh, int kt) {
    char* dst = gsm + 65536 + buf*16384 + kh*8192 + t*16;
    const bf16_t* src = Bb + (long)rowS[0]*K + kt*64 + kh*32 + colS[0];
    __builtin_amdgcn_global_load_lds((const GLOBAL_AS void*)src,
        (LDS_AS void*)dst, 16, 0, 0);
  };

  stageA(0,0,0); stageB(0,0,0); stageA(0,1,0); stageB(0,1,0);
  asm volatile("s_waitcnt vmcnt(3)" ::: "memory");
  __builtin_amdgcn_s_barrier();

  int cb = 0;
  const int KT = K >> 6;
  for (int kt=0; kt<KT; ++kt) {
    const int ktn = (kt+1 < KT) ? kt+1 : kt;
    const char* abuf = gsm + cb*32768;
    const char* bbuf = gsm + 65536 + cb*16384;

    #pragma unroll
    for (int kh=0; kh<2; kh++) {
      bf16x8 af[8], bfr[2];
      #pragma unroll
      for (int j=0;j<8;j++)
        af[j] = *(const bf16x8*)(abuf + kh*16384 + (wm*8+j)*1024 + aoff);
      #pragma unroll
      for (int n=0;n<2;n++)
        bfr[n] = *(const bf16x8*)(bbuf + kh*8192 + (wn*2+n)*1024 + aoff);
      stageA(cb^1, kh, ktn);
      stageB(cb^1, kh, ktn);
      asm volatile("s_waitcnt vmcnt(3)" ::: "memory");
      __builtin_amdgcn_sched_barrier(0);
      __builtin_amdgcn_s_barrier();
      asm volatile("s_waitcnt lgkmcnt(0)" ::: "memory");
      __builtin_amdgcn_sched_barrier(0);
      __builtin_amdgcn_s_setprio(1);
      #pragma unroll
      for (int j=0;j<8;j++)
        #pragma unroll
        for (int n=0;n<2;n++)
          acc[j][n] = MFMA16(af[j], bfr[n], acc[j][n]);
      __builtin_amdgcn_s_setprio(0);
    }
    cb ^= 1;
  }
  __syncthreads();

  #pragma unroll
  for (int mi=0;mi<8;mi++) {
    #pragma unroll
    for (int ni=0;ni<2;ni++) {
      long row = bm*256 + wm*128 + mi*16 + fq*4;
      long col = bn*128 + wn*32 + ni*16 + fr;
      #pragma unroll
      for (int r=0;r<4;r++) {
        float v = acc[mi][ni][r];
        if (OUT_BF16) ((bf16_t*)Cp)[(row+r)*(long)N + col] = (bf16_t)v;
        else          ((float*)Cp)[(row+r)*(long)N + col] = v;
      }
    }
  }
}

// ---------------------------------------------------------------------------
// conv(K=4 causal depthwise) + bias + silu + q/k l2norm + transpose (v3 LDS).
// ---------------------------------------------------------------------------
__global__ __launch_bounds__(256) void conv_norm_kernel(
    const bf16_t* __restrict__ mixed, const float* __restrict__ cw,
    const float* __restrict__ cb, bf16_t* __restrict__ q_t,
    bf16_t* __restrict__ k_t, bf16_t* __restrict__ v_t)
{
  __shared__ bf16_t lx[35*392];
  __shared__ float4 lcw[384];
  __shared__ float  lcb[384];
  const int blk = blockIdx.x;
  const int st = blk & 63;
  const int h  = (blk >> 6) & 15;
  const int b  = blk >> 10;
  const int t  = threadIdx.x;
  const int s0 = st*32;

  for (int i = t; i < 384; i += 256) {
    int seg = i >> 7, d = i & 127;
    int gch = seg*2048 + h*128 + d;
    lcw[i] = ((const float4*)cw)[gch];
    lcb[i] = cb[gch];
  }
  for (int idx = t; idx < 1680; idx += 256) {
    int chunk = idx >> 4, e = idx & 15;
    int row = chunk / 3, seg = chunk - row*3;
    int s2 = s0 - 3 + row;
    bf16x8 v8;
    if (s2 >= 0) {
      v8 = *(const bf16x8*)(mixed + ((long)b*SS + s2)*CONVC + seg*2048 + h*128 + e*8);
    } else {
      #pragma unroll
      for (int j=0;j<8;j++) v8[j] = (bf16_t)0.f;
    }
    *(bf16x8*)&lx[row*392 + seg*128 + e*8] = v8;
  }
  __syncthreads();

  const int s_local = t >> 3, dg = t & 7;
  const int s  = s0 + s_local;
  const int d0 = dg*16;
  const long obase = ((long)(b*HH + h)*SS + s)*128 + d0;

  float scl_q = 0.f, scl_k = 0.f;

  #pragma unroll
  for (int seg=0; seg<3; ++seg) {
    bf16x8 xr[4][2];
    #pragma unroll
    for (int tp=0; tp<4; ++tp) {
      const bf16_t* p = &lx[(s_local + tp)*392 + seg*128 + d0];
      xr[tp][0] = *(const bf16x8*)p;
      xr[tp][1] = *(const bf16x8*)(p + 8);
    }
    float a[16];
    #pragma unroll
    for (int half=0; half<2; ++half) {
      #pragma unroll
      for (int j=0;j<8;j++) {
        int ch = seg*128 + d0 + half*8 + j;
        float4 wj = lcw[ch];
        float v = lcb[ch]
                + (float)xr[0][half][j]*wj.x + (float)xr[1][half][j]*wj.y
                + (float)xr[2][half][j]*wj.z + (float)xr[3][half][j]*wj.w;
        a[half*8+j] = v * (1.f/(1.f+expf(-v)));
      }
    }
    if (seg < 2) {
      float ss = 0.f;
      #pragma unroll
      for (int j=0;j<16;j++) ss += a[j]*a[j];
      ss += __shfl_xor(ss, 1);
      ss += __shfl_xor(ss, 2);
      ss += __shfl_xor(ss, 4);
      float scl = rsqrtf(ss + 1e-6f);
      if (seg == 0) scl_q = scl * 0.08838834764831845f;
      else          scl_k = scl;
    }
    {
      bf16_t* outp = (seg==0) ? (q_t + obase) : (seg==1) ? (k_t + obase) : (v_t + obase);
      float scl = (seg==0) ? scl_q : (seg==1) ? scl_k : 1.f;
      bf16x8 o0, o1;
      #pragma unroll
      for (int j=0;j<8;j++) { o0[j] = (bf16_t)(a[j]*scl); o1[j] = (bf16_t)(a[8+j]*scl); }
      *(bf16x8*)outp = o0;
      *(bf16x8*)(outp + 8) = o1;
    }
  }
}

// ---------------------------------------------------------------------------
// Phase A (per bh,chunk): build Tp/Aq/TV/KTs/pv/PC into cdata.
// ---------------------------------------------------------------------------
__global__ __launch_bounds__(256) void chunkA_kernel(
    const bf16_t* __restrict__ q_t, const bf16_t* __restrict__ k_t,
    const bf16_t* __restrict__ v_t, const float2* __restrict__ gb_t,
    char* __restrict__ cdata)
{
  extern __shared__ char smem[];
  bf16_t* lK  = (bf16_t*)(smem);            // [64][136]
  bf16_t* lQV = (bf16_t*)(smem + 17408);    // lQ [64][136], later lVT [128][72]
  float*  lLf = (float*)(smem + 35840);     // [64][65]
  float*  lXf = (float*)(smem + 52480);     // [64][65]
  float*  gcv = (float*)(smem + 69120);     // [64]
  float*  pvv = (float*)(smem + 69376);     // [64]
  float*  bvv = (float*)(smem + 69632);     // [64]
  float*  evv = (float*)(smem + 69888);     // [64]
  float*  lP  = (float*)(smem + 70144);     // [3][16][17]

  const int cd = blockIdx.x;
  const int bh = cd >> 5, c = cd & 31;
  const int t = threadIdx.x;
  const int lane = t & 63, w = t >> 6;
  const int fr = lane & 15, fq = lane >> 4;

  const bf16_t* kg = k_t + ((long)bh*SS + c*CH)*128;
  const bf16_t* qg = q_t + ((long)bh*SS + c*CH)*128;
  const bf16_t* vg = v_t + ((long)bh*SS + c*CH)*128;
  char* cdp = cdata + (long)cd*CD_STRIDE;

  #pragma unroll
  for (int ib=0; ib<4; ib++) {
    int e0 = (t + 256*ib)*8;
    int r = e0 >> 7, cc = e0 & 127;
    *(bf16x8*)&lK[r*136+cc]  = *(const bf16x8*)(kg + e0);
    *(bf16x8*)&lQV[r*136+cc] = *(const bf16x8*)(qg + e0);
  }
  if (t < 64) {
    float2 gb = gb_t[(long)bh*SS + c*CH + t];
    gcv[t] = gb.x;
    bvv[t] = gb.y;
  }
  __syncthreads();
  if (t < 64) {
    float g = gcv[t];
    #pragma unroll
    for (int off=1; off<64; off<<=1) {
      float n = __shfl_up(g, off);
      if (lane >= off) g += n;
    }
    gcv[t] = g;
  }
  __syncthreads();
  if (t < 64) {
    pvv[t] = expf(gcv[t]);
    evv[t] = expf(gcv[63] - gcv[t]);
  }

  {
    f32x4 accG[4], accQ[4];
    #pragma unroll
    for (int tn=0;tn<4;tn++){ accG[tn]=(f32x4){0,0,0,0}; accQ[tn]=(f32x4){0,0,0,0}; }
    #pragma unroll
    for (int ks=0;ks<4;ks++) {
      bf16x8 aK = *(const bf16x8*)&lK[(w*16+fr)*136 + fq*8 + ks*32];
      bf16x8 aQ = *(const bf16x8*)&lQV[(w*16+fr)*136 + fq*8 + ks*32];
      #pragma unroll
      for (int tn=0;tn<4;tn++) {
        bf16x8 bK = *(const bf16x8*)&lK[(tn*16+fr)*136 + fq*8 + ks*32];
        accG[tn] = MFMA16(aK, bK, accG[tn]);
        accQ[tn] = MFMA16(aQ, bK, accQ[tn]);
      }
    }
    bf16_t* aqg = (bf16_t*)(cdp + CD_AQ);
    #pragma unroll
    for (int tn=0;tn<4;tn++) {
      #pragma unroll
      for (int r=0;r<4;r++) {
        int tt = w*16 + fq*4 + r;
        int ii = tn*16 + fr;
        float er = expf(gcv[tt] - gcv[ii]);
        lLf[tt*65 + ii] = (ii < tt) ? bvv[tt]*er*accG[tn][r] : 0.f;
        aqg[tt*64 + ii] = (bf16_t)((ii <= tt) ? er*accQ[tn][r] : 0.f);
      }
    }
  }

  {
    const int a = w;
    float* Ub = lXf + (a*16)*65 + a*16;
    const float* Lb = lLf + (a*16)*65 + a*16;
    if (lane < 16) Ub[lane] = (lane == 0) ? 1.f : 0.f;
    for (int bb = a+1; bb < 4; bb++)
      for (int e = lane; e < 256; e += 64)
        lXf[(a*16 + (e>>4))*65 + bb*16 + (e&15)] = 0.f;
    if (lane < 16) {
      const int cc = lane;
      for (int i=1; i<16; i++) {
        float s = 0.f;
        for (int j=0; j<i; j++) s += Lb[i*65+j] * Ub[j*65+cc];
        Ub[i*65+cc] = ((i==cc)?1.f:0.f) - s;
      }
    }
  }
  __syncthreads();

  bf16_t* lVT = lQV;   // [128][72]
  {
    const int m = t & 15;
    #pragma unroll
    for (int ib=0; ib<4; ib++) {
      int e0 = (t + 256*ib)*8;
      int r = e0 >> 7, cc = e0 & 127;
      bf16x8 v8 = *(const bf16x8*)(vg + e0);
      #pragma unroll
      for (int e=0;e<8;e++) {
        int ee = (e + m) & 7;
        lVT[(cc+ee)*72 + r] = v8[ee];
      }
    }
  }

  {
    const int i = t >> 4, j = t & 15;
    #pragma unroll
    for (int bb=0; bb<3; bb++) {
      float s = 0.f;
      const float* Mrow = lLf + ((bb+1)*16 + i)*65 + bb*16;
      const float* Ucol = lXf + (bb*16)*65 + bb*16 + j;
      #pragma unroll
      for (int k=0;k<16;k++) s += Mrow[k] * Ucol[k*65];
      lP[bb*272 + i*17 + j] = s;
    }
  }
  __syncthreads();
  {
    const int i = t >> 4, j = t & 15;
    #pragma unroll
    for (int bb=0; bb<3; bb++) {
      float s = 0.f;
      const float* Urow = lXf + ((bb+1)*16 + i)*65 + (bb+1)*16;
      const float* Pcol = lP + bb*272 + j;
      #pragma unroll
      for (int k=0;k<16;k++) s += Urow[k] * Pcol[k*17];
      lXf[((bb+1)*16 + i)*65 + bb*16 + j] = -s;
    }
  }
  __syncthreads();
  {
    const int i = t >> 4, j = t & 15;
    #pragma unroll
    for (int bb=0; bb<2; bb++) {
      float s = 0.f;
      const float* M0 = lLf + ((bb+2)*16 + i)*65 + bb*16;
      const float* U0 = lXf + (bb*16)*65 + bb*16 + j;
      const float* M1 = lLf + ((bb+2)*16 + i)*65 + (bb+1)*16;
      const float* T1 = lXf + ((bb+1)*16)*65 + bb*16 + j;
      #pragma unroll
      for (int k=0;k<16;k++) s += M0[k]*U0[k*65] + M1[k]*T1[k*65];
      lP[bb*272 + i*17 + j] = s;
    }
  }
  __syncthreads();
  {
    const int i = t >> 4, j = t & 15;
    #pragma unroll
    for (int bb=0; bb<2; bb++) {
      float s = 0.f;
      const float* Urow = lXf + ((bb+2)*16 + i)*65 + (bb+2)*16;
      const float* Pcol = lP + bb*272 + j;
      #pragma unroll
      for (int k=0;k<16;k++) s += Urow[k] * Pcol[k*17];
      lXf[((bb+2)*16 + i)*65 + bb*16 + j] = -s;
    }
  }
  __syncthreads();
  {
    const int i = t >> 4, j = t & 15;
    float s = 0.f;
    const float* M0 = lLf + (48 + i)*65 + 0;
    const float* U0 = lXf + 0*65 + j;
    const float* M1 = lLf + (48 + i)*65 + 16;
    const float* T1 = lXf + 16*65 + j;
    const float* M2 = lLf + (48 + i)*65 + 32;
    const float* T2 = lXf + 32*65 + j;
    #pragma unroll
    for (int k=0;k<16;k++) s += M0[k]*U0[k*65] + M1[k]*T1[k*65] + M2[k]*T2[k*65];
    lP[i*17 + j] = s;
  }
  __syncthreads();
  {
    const int i = t >> 4, j = t & 15;
    float s = 0.f;
    const float* Urow = lXf + (48 + i)*65 + 48;
    const float* Pcol = lP + j;
    #pragma unroll
    for (int k=0;k<16;k++) s += Urow[k] * Pcol[k*17];
    lXf[(48 + i)*65 + j] = -s;
  }
  __syncthreads();

  bf16_t* lXb = (bf16_t*)lLf;   // [64][72]
  {
    bf16_t* tpg = (bf16_t*)(cdp + CD_TP);
    #pragma unroll
    for (int ib=0; ib<16; ib++) {
      int idx = t + ib*256; int r = idx>>6, cc = idx&63;
      float xv = lXf[r*65+cc] * bvv[cc];
      tpg[r*64+cc] = (bf16_t)(xv * pvv[cc]);
      lXb[r*72+cc] = (bf16_t)xv;
    }
  }
  __syncthreads();

  {
    f32x4 acc[8];
    #pragma unroll
    for (int tn=0;tn<8;tn++) acc[tn]=(f32x4){0,0,0,0};
    #pragma unroll
    for (int ks=0;ks<2;ks++) {
      bf16x8 aX = *(const bf16x8*)&lXb[(w*16+fr)*72 + fq*8 + ks*32];
      #pragma unroll
      for (int tn=0;tn<8;tn++) {
        bf16x8 bV = *(const bf16x8*)&lVT[(tn*16+fr)*72 + fq*8 + ks*32];
        acc[tn] = MFMA16(aX, bV, acc[tn]);
      }
    }
    bf16_t* tvg = (bf16_t*)(cdp + CD_TV);
    #pragma unroll
    for (int tn=0;tn<8;tn++)
      #pragma unroll
      for (int r=0;r<4;r++) {
        int tt = w*16 + fq*4 + r, dv = tn*16 + fr;
        tvg[tt*128 + dv] = (bf16_t)acc[tn][r];
      }
  }

  {
    bf16_t* ktg = (bf16_t*)(cdp + CD_KTS);
    int dk = t >> 1, c0 = (t & 1)*32;
    bf16_t tmp[32];
    #pragma unroll
    for (int i2=0;i2<32;i2++) {
      int i = c0 + i2;
      tmp[i2] = (bf16_t)((float)lK[i*136 + dk] * evv[i]);
    }
    #pragma unroll
    for (int s8=0;s8<4;s8++)
      *(bf16x8*)&ktg[dk*64 + c0 + s8*8] = *(bf16x8*)&tmp[s8*8];
  }
  if (t < 64) ((float*)(cdp + CD_PV))[t] = pvv[t];
  if (t == 0) *((float*)(cdp + CD_PC)) = expf(gcv[63]);
}

// ---------------------------------------------------------------------------
// Phase S v4 (serial over 32 chunks; 256 blocks = 32 bh x 8 dv-splits):
//   v3 + raw LDS-only barriers (no vmcnt drain at barriers -> prefetch
//   global loads stay in flight across phases) + STAGE_WRITE moved before
//   barrier B (drains during the barrier wait).
// LDS map unchanged from v3 (143232 B, 1 block/CU).
// ---------------------------------------------------------------------------
__global__ __launch_bounds__(256) void chunkS_kernel(
    const bf16_t* __restrict__ q_t, const bf16_t* __restrict__ k_t,
    const char* __restrict__ cdata, bf16_t* __restrict__ obuf)
{
  extern __shared__ char smem[];
  float*  lS  = (float*)(smem);              // [16][129]
  bf16_t* lSb = (bf16_t*)(smem + 8320);      // [16][136]
  bf16_t* lXT = (bf16_t*)(smem + 137600);    // [16][88]
  bf16_t* lDT = (bf16_t*)(smem + 140416);    // [16][88]

  const int bid = blockIdx.x;
  const int lb  = (bid & 7)*32 + (bid >> 3);
  const int bh = lb >> 3, sp = lb & 7;
  const int dv0 = sp*16;
  const int b = bh >> 4, h = bh & 15;
  const int t = threadIdx.x, lane = t & 63, w = t >> 6;
  const int fr = lane & 15, fq = lane >> 4;

  #pragma unroll
  for (int ib=0; ib<8; ib++) {
    int idx = t + ib*256; int r = idx>>7, cc = idx&127;
    lS[r*129+cc] = 0.f;
    lSb[r*136+cc] = (bf16_t)0.f;
  }

  const bf16_t* kg = k_t + (long)bh*SS*128;
  const bf16_t* qg = q_t + (long)bh*SS*128;

  bf16x8 kr0,kr1,kr2,kr3, qr0,qr1,qr2,qr3, kt0,kt1,kt2,kt3, tp0,tp1;

#define STAGE_LOAD(CSRC)                                                       \
  {                                                                            \
    const char* cdl = cdata + (long)(bh*NCH + (CSRC))*CD_STRIDE;               \
    const bf16_t* kl = kg + (long)(CSRC)*CH*128;                               \
    const bf16_t* ql = qg + (long)(CSRC)*CH*128;                               \
    const bf16_t* ktl = (const bf16_t*)(cdl + CD_KTS);                         \
    const bf16_t* tpl = (const bf16_t*)(cdl + CD_TP);                          \
    int e0 = t*8, e1 = (t+256)*8, e2 = (t+512)*8, e3 = (t+768)*8;              \
    kr0 = *(const bf16x8*)(kl + e0); kr1 = *(const bf16x8*)(kl + e1);          \
    kr2 = *(const bf16x8*)(kl + e2); kr3 = *(const bf16x8*)(kl + e3);          \
    qr0 = *(const bf16x8*)(ql + e0); qr1 = *(const bf16x8*)(ql + e1);          \
    qr2 = *(const bf16x8*)(ql + e2); qr3 = *(const bf16x8*)(ql + e3);          \
    kt0 = *(const bf16x8*)(ktl + e0); kt1 = *(const bf16x8*)(ktl + e1);        \
    kt2 = *(const bf16x8*)(ktl + e2); kt3 = *(const bf16x8*)(ktl + e3);        \
    tp0 = *(const bf16x8*)(tpl + e0); tp1 = *(const bf16x8*)(tpl + e1);        \
  }

#define STAGE_WRITE(BASE)                                                      \
  {                                                                            \
    char* _bp = (BASE);                                                        \
    bf16_t* _lK  = (bf16_t*)_bp;                                               \
    bf16_t* _lQ  = (bf16_t*)(_bp + 17408);                                     \
    bf16_t* _lTp = (bf16_t*)(_bp + 34816);                                     \
    bf16_t* _lKT = (bf16_t*)(_bp + 44032);                                     \
    int e0 = t*8, e1 = (t+256)*8, e2 = (t+512)*8, e3 = (t+768)*8;              \
    *(bf16x8*)&_lK[(e0>>7)*136 + (e0&127)] = kr0;                              \
    *(bf16x8*)&_lK[(e1>>7)*136 + (e1&127)] = kr1;                              \
    *(bf16x8*)&_lK[(e2>>7)*136 + (e2&127)] = kr2;                              \
    *(bf16x8*)&_lK[(e3>>7)*136 + (e3&127)] = kr3;                              \
    *(bf16x8*)&_lQ[(e0>>7)*136 + (e0&127)] = qr0;                              \
    *(bf16x8*)&_lQ[(e1>>7)*136 + (e1&127)] = qr1;                              \
    *(bf16x8*)&_lQ[(e2>>7)*136 + (e2&127)] = qr2;                              \
    *(bf16x8*)&_lQ[(e3>>7)*136 + (e3&127)] = qr3;                              \
    *(bf16x8*)&_lKT[(e0>>6)*72 + (e0&63)] = kt0;                               \
    *(bf16x8*)&_lKT[(e1>>6)*72 + (e1&63)] = kt1;                               \
    *(bf16x8*)&_lKT[(e2>>6)*72 + (e2&63)] = kt2;                               \
    *(bf16x8*)&_lKT[(e3>>6)*72 + (e3&63)] = kt3;                               \
    *(bf16x8*)&_lTp[(e0>>6)*72 + (e0&63)] = tp0;                               \
    *(bf16x8*)&_lTp[(e1>>6)*72 + (e1&63)] = tp1;                               \
  }

  STAGE_LOAD(0);
  STAGE_WRITE(smem + 12672);
  __syncthreads();

  for (int c=0; c<NCH; c++) {
    const int cd = bh*NCH + c;
    const char* cdp = cdata + (long)cd*CD_STRIDE;
    const int cb = c & 1;
    char* rbuf = smem + 12672 + cb*62464;
    bf16_t* lK  = (bf16_t*)rbuf;
    bf16_t* lQ  = (bf16_t*)(rbuf + 17408);
    bf16_t* lTp = (bf16_t*)(rbuf + 34816);
    bf16_t* lKT = (bf16_t*)(rbuf + 44032);

    float tvq0, tvq1, tvq2, tvq3, pc;
    float pvq[4];
    bf16x8 aqr0, aqr1;
    {
      const bf16_t* tvp = (const bf16_t*)(cdp + CD_TV);
      const float* pvp = (const float*)(cdp + CD_PV);
      const bf16_t* aqp = (const bf16_t*)(cdp + CD_AQ);
      tvq0 = (float)tvp[(w*16+fq*4+0)*128 + dv0 + fr];
      tvq1 = (float)tvp[(w*16+fq*4+1)*128 + dv0 + fr];
      tvq2 = (float)tvp[(w*16+fq*4+2)*128 + dv0 + fr];
      tvq3 = (float)tvp[(w*16+fq*4+3)*128 + dv0 + fr];
      #pragma unroll
      for (int r=0;r<4;r++) pvq[r] = pvp[w*16+fq*4+r];
      pc = *(const float*)(cdp + CD_PC);
      aqr0 = *(const bf16x8*)(aqp + (w*16+fr)*64 + fq*8);
      aqr1 = *(const bf16x8*)(aqp + (w*16+fr)*64 + fq*8 + 32);
    }
    const int cn = (c+1 < NCH) ? c+1 : c;
    STAGE_LOAD(cn);

    // phase 1: X = K S^T-slice, Xq = Q S^T-slice
    f32x4 aX = {0,0,0,0}, aXq = {0,0,0,0};
    #pragma unroll
    for (int ks=0; ks<4; ks++) {
      bf16x8 bS = *(const bf16x8*)&lSb[fr*136 + fq*8 + ks*32];
      bf16x8 aK = *(const bf16x8*)&lK[(w*16+fr)*136 + fq*8 + ks*32];
      bf16x8 aQ = *(const bf16x8*)&lQ[(w*16+fr)*136 + fq*8 + ks*32];
      aX  = MFMA16(aK, bS, aX);
      aXq = MFMA16(aQ, bS, aXq);
    }
    #pragma unroll
    for (int r=0;r<4;r++)
      lXT[fr*88 + (w*16+fq*4+r)] = (bf16_t)aX[r];
    BAR_LDS();   // A (LDS-only: prefetch loads stay in flight)

    // phase 2: D = TV - Tp X
    {
      f32x4 aD = {0,0,0,0};
      #pragma unroll
      for (int ks=0; ks<2; ks++) {
        bf16x8 aT = *(const bf16x8*)&lTp[(w*16+fr)*72 + fq*8 + ks*32];
        bf16x8 bX = *(const bf16x8*)&lXT[fr*88 + fq*8 + ks*32];
        aD = MFMA16(aT, bX, aD);
      }
      lDT[fr*88 + (w*16+fq*4+0)] = (bf16_t)(tvq0 - aD[0]);
      lDT[fr*88 + (w*16+fq*4+1)] = (bf16_t)(tvq1 - aD[1]);
      lDT[fr*88 + (w*16+fq*4+2)] = (bf16_t)(tvq2 - aD[2]);
      lDT[fr*88 + (w*16+fq*4+3)] = (bf16_t)(tvq3 - aD[3]);
    }

    // write next chunk's staging into the other buffer (safe: that buffer's
    // last readers finished at the previous chunk's barrier C). The vmcnt
    // waits for the prefetch loads land here, after phases 1-2 hid latency.
    STAGE_WRITE(smem + 12672 + (cb^1)*62464);
    BAR_LDS();   // B

    // phase 3: S = pc*S + D^T KTs^T (fold + inline bf16); O written directly
    {
      f32x4 aS0 = {0,0,0,0}, aS1 = {0,0,0,0}, aO = {0,0,0,0};
      #pragma unroll
      for (int ks=0; ks<2; ks++) {
        bf16x8 aDd = *(const bf16x8*)&lDT[fr*88 + fq*8 + ks*32];
        bf16x8 bK0 = *(const bf16x8*)&lKT[(w*32+fr)*72 + fq*8 + ks*32];
        bf16x8 bK1 = *(const bf16x8*)&lKT[(w*32+16+fr)*72 + fq*8 + ks*32];
        bf16x8 aA  = (ks==0) ? aqr0 : aqr1;
        aS0 = MFMA16(aDd, bK0, aS0);
        aS1 = MFMA16(aDd, bK1, aS1);
        aO  = MFMA16(aA,  aDd, aO);
      }
      #pragma unroll
      for (int r=0;r<4;r++) {
        int dvr = fq*4 + r;
        float s0 = lS[dvr*129 + w*32 + fr]      * pc + aS0[r];
        float s1 = lS[dvr*129 + w*32 + 16 + fr] * pc + aS1[r];
        lS[dvr*129 + w*32 + fr]      = s0;
        lS[dvr*129 + w*32 + 16 + fr] = s1;
        lSb[dvr*136 + w*32 + fr]      = (bf16_t)s0;
        lSb[dvr*136 + w*32 + 16 + fr] = (bf16_t)s1;
      }
      #pragma unroll
      for (int r=0;r<4;r++) {
        int tt = w*16+fq*4+r;
        long tok = (long)b*SS + c*CH + tt;
        float ov = pvq[r]*aXq[r] + aO[r];
        obuf[(tok*HH + h)*128 + dv0 + fr] = (bf16_t)ov;
      }
    }
    BAR_LDS();   // C
  }
#undef STAGE_LOAD
#undef STAGE_WRITE
}

// ---------------------------------------------------------------------------
// RMSNorm over DV + (1+nw) + silu(z) gate; wave-per-row, no LDS/barrier.
// ---------------------------------------------------------------------------
__global__ __launch_bounds__(256) void norm_gate_kernel(
    const bf16_t* __restrict__ o, const bf16_t* __restrict__ zfull,
    const float* __restrict__ nw, bf16_t* __restrict__ og)
{
  const long row = (long)blockIdx.x*4 + (threadIdx.x >> 6);  // (b*S+s)*H + h
  const int lane = threadIdx.x & 63;
  const long tok = row >> 4;
  const int h = row & 15;
  bf16x2 xv = *(const bf16x2*)(o + row*128 + lane*2);
  float x0 = (float)xv[0], x1 = (float)xv[1];
  float ss = x0*x0 + x1*x1;
  #pragma unroll
  for (int off=32; off>=1; off>>=1) ss += __shfl_xor(ss, off);
  float rr = rsqrtf(ss*(1.f/128.f) + 1e-6f);
  bf16x2 zv = *(const bf16x2*)(zfull + tok*DD + h*128 + lane*2);
  float z0 = (float)zv[0], z1 = (float)zv[1];
  float v0 = x0 * rr * (1.f + nw[lane*2])   * (z0 * (1.f/(1.f+expf(-z0))));
  float v1 = x1 * rr * (1.f + nw[lane*2+1]) * (z1 * (1.f/(1.f+expf(-z1))));
  bf16x2 ov; ov[0] = (bf16_t)v0; ov[1] = (bf16_t)v1;
  *(bf16x2*)(og + row*128 + lane*2) = ov;
}

// ---------------------------------------------------------------------------
extern "C" void kernel_launch(void* const* d_in, const int* in_sizes, int n_in,
                              void* d_out, int out_size, void* d_ws, size_t ws_size,
                              hipStream_t stream)
{
  const float* hs    = (const float*)d_in[0];
  const float* amask = (const float*)d_in[1];
  const float* Wqkv  = (const float*)d_in[2];
  const float* convw = (const float*)d_in[3];
  const float* convb = (const float*)d_in[4];
  const float* Wz    = (const float*)d_in[5];
  const float* Wb    = (const float*)d_in[6];
  const float* Wa    = (const float*)d_in[7];
  const float* dtb   = (const float*)d_in[8];
  const float* Alog  = (const float*)d_in[9];
  const float* nw    = (const float*)d_in[10];
  const float* Wout  = (const float*)d_in[11];

  const size_t MB = 1024*1024;
  char* p = (char*)d_ws;
  auto alloc = [&](size_t bytes) { char* r = p; p += (bytes + 255) & ~(size_t)255; return r; };
  bf16_t* x_bf   = (bf16_t*)alloc(16*MB);   // x_bf
  char*   bigreg = alloc(84*MB);            // wB@0 (32MB), mixed@34MB (48MB); later cdata@0
  bf16_t* wba    = (bf16_t*)alloc(256*1024);// [32][2048] bf16
  bf16_t* woutb  = (bf16_t*)alloc(8*MB);    // Wout bf16
  bf16_t* zbuf   = (bf16_t*)alloc(16*MB);   // [4096][2048]
  bf16_t* q_t    = (bf16_t*)alloc(16*MB);   // q; later og
  bf16_t* k_t    = (bf16_t*)alloc(16*MB);
  bf16_t* v_t    = (bf16_t*)alloc(16*MB);   // v; later obuf
  float2* gb_t   = (float2*)alloc((size_t)BB*HH*SS*8);
  size_t need = (size_t)(p - (char*)d_ws);
  if (ws_size < need) return;   // clean fail (absmax = poison)

  bf16_t* wB      = (bf16_t*)bigreg;              // [8192][2048] bf16
  bf16_t* mixed   = (bf16_t*)(bigreg + 34*MB);    // [4096][6144] bf16
  char*   cdata   = bigreg;                       // after fused GEMM + conv consumed
  bf16_t* obuf    = v_t;                          // after chunkA consumed v_t
  bf16_t* og      = q_t;                          // after chunkS consumed q_t

  cast_all_kernel<<<2048, 256, 0, stream>>>(hs, amask, Wqkv, Wz, Wb, Wa, Wout,
                                            x_bf, wB, wba, woutb);

  betag3_kernel<<<MM/16, 64, 0, stream>>>(x_bf, wba, dtb, Alog, gb_t);

  gemm_fused<<<512, 512, 131072, stream>>>(x_bf, wB, mixed, zbuf, DD, 32);

  conv_norm_kernel<<<BB*HH*(SS/32), 256, 0, stream>>>(mixed, convw, convb, q_t, k_t, v_t);

  chunkA_kernel<<<BB*HH*NCH, 256, 73408, stream>>>(q_t, k_t, v_t, gb_t, cdata);
  chunkS_kernel<<<BB*HH*8, 256, 143232, stream>>>(q_t, k_t, cdata, obuf);

  norm_gate_kernel<<<MM*HH/4, 256, 0, stream>>>(obuf, zbuf, nw, og);

  gemm256<false><<<256, 512, 98304, stream>>>(og, woutb, d_out, MM, DD, DD, 16);
}

// Round 25
// 360.226 us; speedup vs baseline: 1.0386x; 1.0386x over previous
//
#include <hip/hip_runtime.h>
#include <hip/hip_bf16.h>
#include <math.h>

// Problem constants
#define BB 2
#define SS 2048
#define DD 2048
#define HH 16
#define CONVC 6144
#define MM (BB*SS)   // 4096 tokens

// chunked delta-rule constants
#define CH 64        // chunk length
#define NCH 32       // chunks per sequence
#define CD_KTS 0
#define CD_TV  16384
#define CD_TP  32768
#define CD_AQ  40960
#define CD_PV  49152
#define CD_PC  49408
#define CD_STRIDE 49664

typedef __bf16 bf16_t;
typedef __bf16 bf16x8 __attribute__((ext_vector_type(8)));
typedef __bf16 bf16x4 __attribute__((ext_vector_type(4)));
typedef __bf16 bf16x2 __attribute__((ext_vector_type(2)));
typedef float  f32x4  __attribute__((ext_vector_type(4)));

#define GLOBAL_AS __attribute__((address_space(1)))
#define LDS_AS    __attribute__((address_space(3)))

#define MFMA16(a,b,c) __builtin_amdgcn_mfma_f32_16x16x32_bf16((a),(b),(c),0,0,0)

// ---------------------------------------------------------------------------
// cast_all: one grid-stride kernel for every f32->bf16 cast.
// ---------------------------------------------------------------------------
__global__ __launch_bounds__(256) void cast_all_kernel(
    const float* __restrict__ hs, const float* __restrict__ amask,
    const float* __restrict__ Wqkv, const float* __restrict__ Wz,
    const float* __restrict__ Wb, const float* __restrict__ Wa,
    const float* __restrict__ Wout,
    bf16_t* __restrict__ x_bf, bf16_t* __restrict__ wB,
    bf16_t* __restrict__ wba, bf16_t* __restrict__ woutb)
{
  const long N0 = (long)MM*DD/4;            // x
  const long N1 = N0 + (long)CONVC*DD/4;    // Wqkv
  const long N2 = N1 + (long)DD*DD/4;       // Wz
  const long N3 = N2 + 16*DD/4;             // Wb
  const long N4 = N3 + 16*DD/4;             // Wa
  const long N5 = N4 + (long)DD*DD/4;       // Wout
  for (long i = (long)blockIdx.x*256 + threadIdx.x; i < N5; i += (long)gridDim.x*256) {
    const float* src; bf16_t* dst; float m = 1.f;
    if (i < N0)      { long j=i;    src = hs   + j*4; dst = x_bf + j*4; m = amask[(j*4)/DD]; }
    else if (i < N1) { long j=i-N0; src = Wqkv + j*4; dst = wB + j*4; }
    else if (i < N2) { long j=i-N1; src = Wz   + j*4; dst = wB + (size_t)CONVC*DD + j*4; }
    else if (i < N3) { long j=i-N2; src = Wb   + j*4; dst = wba + j*4; }
    else if (i < N4) { long j=i-N3; src = Wa   + j*4; dst = wba + 16*DD + j*4; }
    else             { long j=i-N4; src = Wout + j*4; dst = woutb + j*4; }
    float4 v = *(const float4*)src;
    bf16x4 o4;
    o4[0]=(bf16_t)(v.x*m); o4[1]=(bf16_t)(v.y*m);
    o4[2]=(bf16_t)(v.z*m); o4[3]=(bf16_t)(v.w*m);
    *(bf16x4*)dst = o4;
  }
}

// ---------------------------------------------------------------------------
// betag3 v2: pb/pa via MFMA, split-K across 4 waves (4x latency hiding).
// Each block: 16 tokens; wave w accumulates ks == w (mod 4); LDS reduce.
// ---------------------------------------------------------------------------
__global__ __launch_bounds__(256) void betag3_kernel(
    const bf16_t* __restrict__ xbf, const bf16_t* __restrict__ wba,
    const float* __restrict__ dtb, const float* __restrict__ Alog,
    float2* __restrict__ gb_t)
{
  __shared__ f32x4 red0[4][64];
  __shared__ f32x4 red1[4][64];
  const int t = threadIdx.x;
  const int lane = t & 63, w = t >> 6;
  const int fr = lane & 15, fq = lane >> 4;
  const long tok0 = (long)blockIdx.x*16;

  f32x4 acc0 = {0,0,0,0}, acc1 = {0,0,0,0};
  const bf16_t* ar = xbf + (tok0 + fr)*DD + fq*8;
  const bf16_t* b0 = wba + fr*DD + fq*8;
  const bf16_t* b1 = wba + (16+fr)*DD + fq*8;
  #pragma unroll 4
  for (int k2=0; k2<16; ++k2) {
    int ks = k2*4 + w;
    bf16x8 a8 = *(const bf16x8*)(ar + ks*32);
    bf16x8 p8 = *(const bf16x8*)(b0 + ks*32);
    bf16x8 q8 = *(const bf16x8*)(b1 + ks*32);
    acc0 = MFMA16(a8, p8, acc0);
    acc1 = MFMA16(a8, q8, acc1);
  }
  red0[w][lane] = acc0;
  red1[w][lane] = acc1;
  __syncthreads();
  if (w == 0) {
    f32x4 s0 = red0[0][lane], s1 = red1[0][lane];
    #pragma unroll
    for (int ww=1; ww<4; ww++) { s0 += red0[ww][lane]; s1 += red1[ww][lane]; }
    const int h = fr;
    float eA = expf(Alog[h]);
    float db = dtb[h];
    #pragma unroll
    for (int r=0;r<4;r++) {
      long tok = tok0 + fq*4 + r;
      int b = (int)(tok >> 11), s = (int)(tok & (SS-1));
      float beta = 1.f/(1.f+expf(-s0[r]));
      float tt2 = s1[r] + db;
      float sp = (tt2 > 20.f) ? tt2 : log1pf(expf(tt2));
      float g  = -eA * sp;
      gb_t[((long)b*HH + h)*SS + s] = make_float2(g, beta);
    }
  }
}

// ---------------------------------------------------------------------------
// Fused 256x256 bf16 GEMM over B = [Wqkv; Wz] (8192 rows, 32 N-tiles).
// 512 blocks = EXACTLY 2 rounds at 1 block/CU.
// ---------------------------------------------------------------------------
__global__ __launch_bounds__(512) void gemm_fused(
    const bf16_t* __restrict__ A, const bf16_t* __restrict__ Bm,
    bf16_t* __restrict__ Cmix, bf16_t* __restrict__ Cz, int K, int nbn)
{
  extern __shared__ char gsm[];   // A: buf0@0, buf1@32768; B: +65536
  const int t    = threadIdx.x;
  const int lane = t & 63;
  const int wid  = t >> 6;
  const int wm   = wid >> 2, wn = wid & 3;
  const int fr   = lane & 15, fq = lane >> 4;

  const int nwg = gridDim.x;
  const int wg  = ((int)blockIdx.x & 7)*(nwg >> 3) + ((int)blockIdx.x >> 3);
  const int grp = wg / (nbn*4);
  const int rem = wg - grp*(nbn*4);
  const long bm = grp*4 + (rem & 3);
  const long bn = rem >> 2;

  int rowS[2], colS[2];
  #pragma unroll
  for (int i=0;i<2;i++) {
    int L  = (i*512 + t)*16;
    int Ls = L ^ (((L>>9)&1)<<5);
    rowS[i] = (Ls>>10)*16 + ((Ls&1023)>>6);
    colS[i] = (Ls&63)>>1;
  }
  const bf16_t* Ab = A  + (bm*256)*(long)K;
  const bf16_t* Bb = Bm + (bn*256)*(long)K;

  f32x4 acc[8][4];
  #pragma unroll
  for (int i=0;i<8;i++)
    #pragma unroll
    for (int j=0;j<4;j++) acc[i][j] = (f32x4){0.f,0.f,0.f,0.f};

  const int aoff = fr*64 + ((fq*16) ^ ((fr&8)<<2));

  auto stage = [&](int buf, int oper, int kh, int kt) {
    const bf16_t* srcb = oper ? Bb : Ab;
    char* dst0 = gsm + oper*65536 + buf*32768 + kh*16384 + t*16;
    #pragma unroll
    for (int i=0;i<2;i++) {
      const bf16_t* src = srcb + (long)rowS[i]*K + kt*64 + kh*32 + colS[i];
      __builtin_amdgcn_global_load_lds((const GLOBAL_AS void*)src,
          (LDS_AS void*)(dst0 + i*8192), 16, 0, 0);
    }
  };

  stage(0,0,0,0); stage(0,1,0,0); stage(0,0,1,0); stage(0,1,1,0);
  asm volatile("s_waitcnt vmcnt(4)" ::: "memory");
  __builtin_amdgcn_s_barrier();

  bf16x8 bfr[4];
  int cb = 0;
  const int KT = K >> 6;
  for (int kt=0; kt<KT; ++kt) {
    const int ktn = (kt+1 < KT) ? kt+1 : kt;
    const char* abuf = gsm + cb*32768;
    const char* bbuf = gsm + 65536 + cb*32768;

    #pragma unroll
    for (int ph=0; ph<4; ph++) {
      const int kh = ph >> 1, mh = ph & 1;
      bf16x8 af[4];
      #pragma unroll
      for (int j=0;j<4;j++)
        af[j] = *(const bf16x8*)(abuf + kh*16384 + (wm*8 + mh*4 + j)*1024 + aoff);
      if (mh == 0) {
        #pragma unroll
        for (int n=0;n<4;n++)
          bfr[n] = *(const bf16x8*)(bbuf + kh*16384 + (wn*4+n)*1024 + aoff);
      }
      stage(cb^1, mh, kh, ktn);
      if (mh == 1) {
        __builtin_amdgcn_sched_barrier(0);
        asm volatile("s_waitcnt vmcnt(4)" ::: "memory");
      }
      __builtin_amdgcn_sched_barrier(0);
      __builtin_amdgcn_s_barrier();
      asm volatile("s_waitcnt lgkmcnt(0)" ::: "memory");
      __builtin_amdgcn_sched_barrier(0);
      __builtin_amdgcn_s_setprio(1);
      #pragma unroll
      for (int j=0;j<4;j++)
        #pragma unroll
        for (int n=0;n<4;n++)
          acc[mh*4+j][n] = MFMA16(af[j], bfr[n], acc[mh*4+j][n]);
      __builtin_amdgcn_s_setprio(0);
    }
    cb ^= 1;
  }
  __syncthreads();

  bf16_t* Co;
  long No, colb;
  if (bn < 24) { Co = Cmix; No = CONVC; colb = bn*256; }
  else         { Co = Cz;   No = DD;    colb = (bn-24)*256; }

  #pragma unroll
  for (int mi=0;mi<8;mi++) {
    #pragma unroll
    for (int ni=0;ni<4;ni++) {
      long row = bm*256 + wm*128 + mi*16 + fq*4;
      long col = colb + wn*64 + ni*16 + fr;
      #pragma unroll
      for (int r=0;r<4;r++)
        Co[(row+r)*No + col] = (bf16_t)acc[mi][ni][r];
    }
  }
}

// ---------------------------------------------------------------------------
// 256x128 bf16 GEMM (out-GEMM: 256 blocks = one full round)
// ---------------------------------------------------------------------------
template<bool OUT_BF16>
__global__ __launch_bounds__(512) void gemm256(
    const bf16_t* __restrict__ A, const bf16_t* __restrict__ Bm,
    void* __restrict__ Cp, int M, int N, int K, int nbn)
{
  extern __shared__ char gsm[];
  const int t    = threadIdx.x;
  const int lane = t & 63;
  const int wid  = t >> 6;
  const int wm   = wid >> 2, wn = wid & 3;
  const int fr   = lane & 15, fq = lane >> 4;

  const int nwg = gridDim.x;
  const int wg  = ((int)blockIdx.x & 7)*(nwg >> 3) + ((int)blockIdx.x >> 3);
  const int grp = wg / (nbn*4);
  const int rem = wg - grp*(nbn*4);
  const long bm = grp*4 + (rem & 3);
  const long bn = rem >> 2;

  int rowS[2], colS[2];
  #pragma unroll
  for (int i=0;i<2;i++) {
    int L  = (i*512 + t)*16;
    int Ls = L ^ (((L>>9)&1)<<5);
    rowS[i] = (Ls>>10)*16 + ((Ls&1023)>>6);
    colS[i] = (Ls&63)>>1;
  }
  const bf16_t* Ab = A  + (bm*256)*(long)K;
  const bf16_t* Bb = Bm + (bn*128)*(long)K;

  f32x4 acc[8][2];
  #pragma unroll
  for (int i=0;i<8;i++) { acc[i][0] = (f32x4){0,0,0,0}; acc[i][1] = (f32x4){0,0,0,0}; }

  const int aoff = fr*64 + ((fq*16) ^ ((fr&8)<<2));

  auto stageA = [&](int buf, int kh, int kt) {
    char* dst0 = gsm + buf*32768 + kh*16384 + t*16;
    #pragma unroll
    for (int i=0;i<2;i++) {
      const bf16_t* src = Ab + (long)rowS[i]*K + kt*64 + kh*32 + colS[i];
      __builtin_amdgcn_global_load_lds((const GLOBAL_AS void*)src,
          (LDS_AS void*)(dst0 + i*8192), 16, 0, 0);
    }
  };
  auto stageB = [&](int buf, int kh, int kt) {
    char* dst = gsm + 65536 + buf*16384 + kh*8192 + t*16;
    const bf16_t* src = Bb + (long)rowS[0]*K + kt*64 + kh*32 + colS[0];
    __builtin_amdgcn_global_load_lds((const GLOBAL_AS void*)src,
        (LDS_AS void*)dst, 16, 0, 0);
  };

  stageA(0,0,0); stageB(0,0,0); stageA(0,1,0); stageB(0,1,0);
  asm volatile("s_waitcnt vmcnt(3)" ::: "memory");
  __builtin_amdgcn_s_barrier();

  int cb = 0;
  const int KT = K >> 6;
  for (int kt=0; kt<KT; ++kt) {
    const int ktn = (kt+1 < KT) ? kt+1 : kt;
    const char* abuf = gsm + cb*32768;
    const char* bbuf = gsm + 65536 + cb*16384;

    #pragma unroll
    for (int kh=0; kh<2; kh++) {
      bf16x8 af[8], bfr[2];
      #pragma unroll
      for (int j=0;j<8;j++)
        af[j] = *(const bf16x8*)(abuf + kh*16384 + (wm*8+j)*1024 + aoff);
      #pragma unroll
      for (int n=0;n<2;n++)
        bfr[n] = *(const bf16x8*)(bbuf + kh*8192 + (wn*2+n)*1024 + aoff);
      stageA(cb^1, kh, ktn);
      stageB(cb^1, kh, ktn);
      asm volatile("s_waitcnt vmcnt(3)" ::: "memory");
      __builtin_amdgcn_sched_barrier(0);
      __builtin_amdgcn_s_barrier();
      asm volatile("s_waitcnt lgkmcnt(0)" ::: "memory");
      __builtin_amdgcn_sched_barrier(0);
      __builtin_amdgcn_s_setprio(1);
      #pragma unroll
      for (int j=0;j<8;j++)
        #pragma unroll
        for (int n=0;n<2;n++)
          acc[j][n] = MFMA16(af[j], bfr[n], acc[j][n]);
      __builtin_amdgcn_s_setprio(0);
    }
    cb ^= 1;
  }
  __syncthreads();

  #pragma unroll
  for (int mi=0;mi<8;mi++) {
    #pragma unroll
    for (int ni=0;ni<2;ni++) {
      long row = bm*256 + wm*128 + mi*16 + fq*4;
      long col = bn*128 + wn*32 + ni*16 + fr;
      #pragma unroll
      for (int r=0;r<4;r++) {
        float v = acc[mi][ni][r];
        if (OUT_BF16) ((bf16_t*)Cp)[(row+r)*(long)N + col] = (bf16_t)v;
        else          ((float*)Cp)[(row+r)*(long)N + col] = v;
      }
    }
  }
}

// ---------------------------------------------------------------------------
// conv(K=4 causal depthwise) + bias + silu + q/k l2norm + transpose (v3 LDS).
// ---------------------------------------------------------------------------
__global__ __launch_bounds__(256) void conv_norm_kernel(
    const bf16_t* __restrict__ mixed, const float* __restrict__ cw,
    const float* __restrict__ cb, bf16_t* __restrict__ q_t,
    bf16_t* __restrict__ k_t, bf16_t* __restrict__ v_t)
{
  __shared__ bf16_t lx[35*392];
  __shared__ float4 lcw[384];
  __shared__ float  lcb[384];
  const int blk = blockIdx.x;
  const int st = blk & 63;
  const int h  = (blk >> 6) & 15;
  const int b  = blk >> 10;
  const int t  = threadIdx.x;
  const int s0 = st*32;

  for (int i = t; i < 384; i += 256) {
    int seg = i >> 7, d = i & 127;
    int gch = seg*2048 + h*128 + d;
    lcw[i] = ((const float4*)cw)[gch];
    lcb[i] = cb[gch];
  }
  for (int idx = t; idx < 1680; idx += 256) {
    int chunk = idx >> 4, e = idx & 15;
    int row = chunk / 3, seg = chunk - row*3;
    int s2 = s0 - 3 + row;
    bf16x8 v8;
    if (s2 >= 0) {
      v8 = *(const bf16x8*)(mixed + ((long)b*SS + s2)*CONVC + seg*2048 + h*128 + e*8);
    } else {
      #pragma unroll
      for (int j=0;j<8;j++) v8[j] = (bf16_t)0.f;
    }
    *(bf16x8*)&lx[row*392 + seg*128 + e*8] = v8;
  }
  __syncthreads();

  const int s_local = t >> 3, dg = t & 7;
  const int s  = s0 + s_local;
  const int d0 = dg*16;
  const long obase = ((long)(b*HH + h)*SS + s)*128 + d0;

  float scl_q = 0.f, scl_k = 0.f;

  #pragma unroll
  for (int seg=0; seg<3; ++seg) {
    bf16x8 xr[4][2];
    #pragma unroll
    for (int tp=0; tp<4; ++tp) {
      const bf16_t* p = &lx[(s_local + tp)*392 + seg*128 + d0];
      xr[tp][0] = *(const bf16x8*)p;
      xr[tp][1] = *(const bf16x8*)(p + 8);
    }
    float a[16];
    #pragma unroll
    for (int half=0; half<2; ++half) {
      #pragma unroll
      for (int j=0;j<8;j++) {
        int ch = seg*128 + d0 + half*8 + j;
        float4 wj = lcw[ch];
        float v = lcb[ch]
                + (float)xr[0][half][j]*wj.x + (float)xr[1][half][j]*wj.y
                + (float)xr[2][half][j]*wj.z + (float)xr[3][half][j]*wj.w;
        a[half*8+j] = v * (1.f/(1.f+expf(-v)));
      }
    }
    if (seg < 2) {
      float ss = 0.f;
      #pragma unroll
      for (int j=0;j<16;j++) ss += a[j]*a[j];
      ss += __shfl_xor(ss, 1);
      ss += __shfl_xor(ss, 2);
      ss += __shfl_xor(ss, 4);
      float scl = rsqrtf(ss + 1e-6f);
      if (seg == 0) scl_q = scl * 0.08838834764831845f;
      else          scl_k = scl;
    }
    {
      bf16_t* outp = (seg==0) ? (q_t + obase) : (seg==1) ? (k_t + obase) : (v_t + obase);
      float scl = (seg==0) ? scl_q : (seg==1) ? scl_k : 1.f;
      bf16x8 o0, o1;
      #pragma unroll
      for (int j=0;j<8;j++) { o0[j] = (bf16_t)(a[j]*scl); o1[j] = (bf16_t)(a[8+j]*scl); }
      *(bf16x8*)outp = o0;
      *(bf16x8*)(outp + 8) = o1;
    }
  }
}

// ---------------------------------------------------------------------------
// Phase A (per bh,chunk): build Tp/Aq/TV/KTs/pv/PC into cdata.
// ---------------------------------------------------------------------------
__global__ __launch_bounds__(256) void chunkA_kernel(
    const bf16_t* __restrict__ q_t, const bf16_t* __restrict__ k_t,
    const bf16_t* __restrict__ v_t, const float2* __restrict__ gb_t,
    char* __restrict__ cdata)
{
  extern __shared__ char smem[];
  bf16_t* lK  = (bf16_t*)(smem);            // [64][136]
  bf16_t* lQV = (bf16_t*)(smem + 17408);    // lQ [64][136], later lVT [128][72]
  float*  lLf = (float*)(smem + 35840);     // [64][65]
  float*  lXf = (float*)(smem + 52480);     // [64][65]
  float*  gcv = (float*)(smem + 69120);     // [64]
  float*  pvv = (float*)(smem + 69376);     // [64]
  float*  bvv = (float*)(smem + 69632);     // [64]
  float*  evv = (float*)(smem + 69888);     // [64]
  float*  lP  = (float*)(smem + 70144);     // [3][16][17]

  const int cd = blockIdx.x;
  const int bh = cd >> 5, c = cd & 31;
  const int t = threadIdx.x;
  const int lane = t & 63, w = t >> 6;
  const int fr = lane & 15, fq = lane >> 4;

  const bf16_t* kg = k_t + ((long)bh*SS + c*CH)*128;
  const bf16_t* qg = q_t + ((long)bh*SS + c*CH)*128;
  const bf16_t* vg = v_t + ((long)bh*SS + c*CH)*128;
  char* cdp = cdata + (long)cd*CD_STRIDE;

  #pragma unroll
  for (int ib=0; ib<4; ib++) {
    int e0 = (t + 256*ib)*8;
    int r = e0 >> 7, cc = e0 & 127;
    *(bf16x8*)&lK[r*136+cc]  = *(const bf16x8*)(kg + e0);
    *(bf16x8*)&lQV[r*136+cc] = *(const bf16x8*)(qg + e0);
  }
  if (t < 64) {
    float2 gb = gb_t[(long)bh*SS + c*CH + t];
    gcv[t] = gb.x;
    bvv[t] = gb.y;
  }
  __syncthreads();
  if (t < 64) {
    float g = gcv[t];
    #pragma unroll
    for (int off=1; off<64; off<<=1) {
      float n = __shfl_up(g, off);
      if (lane >= off) g += n;
    }
    gcv[t] = g;
  }
  __syncthreads();
  if (t < 64) {
    pvv[t] = expf(gcv[t]);
    evv[t] = expf(gcv[63] - gcv[t]);
  }

  {
    f32x4 accG[4], accQ[4];
    #pragma unroll
    for (int tn=0;tn<4;tn++){ accG[tn]=(f32x4){0,0,0,0}; accQ[tn]=(f32x4){0,0,0,0}; }
    #pragma unroll
    for (int ks=0;ks<4;ks++) {
      bf16x8 aK = *(const bf16x8*)&lK[(w*16+fr)*136 + fq*8 + ks*32];
      bf16x8 aQ = *(const bf16x8*)&lQV[(w*16+fr)*136 + fq*8 + ks*32];
      #pragma unroll
      for (int tn=0;tn<4;tn++) {
        bf16x8 bK = *(const bf16x8*)&lK[(tn*16+fr)*136 + fq*8 + ks*32];
        accG[tn] = MFMA16(aK, bK, accG[tn]);
        accQ[tn] = MFMA16(aQ, bK, accQ[tn]);
      }
    }
    bf16_t* aqg = (bf16_t*)(cdp + CD_AQ);
    #pragma unroll
    for (int tn=0;tn<4;tn++) {
      #pragma unroll
      for (int r=0;r<4;r++) {
        int tt = w*16 + fq*4 + r;
        int ii = tn*16 + fr;
        float er = expf(gcv[tt] - gcv[ii]);
        lLf[tt*65 + ii] = (ii < tt) ? bvv[tt]*er*accG[tn][r] : 0.f;
        aqg[tt*64 + ii] = (bf16_t)((ii <= tt) ? er*accQ[tn][r] : 0.f);
      }
    }
  }

  {
    const int a = w;
    float* Ub = lXf + (a*16)*65 + a*16;
    const float* Lb = lLf + (a*16)*65 + a*16;
    if (lane < 16) Ub[lane] = (lane == 0) ? 1.f : 0.f;
    for (int bb = a+1; bb < 4; bb++)
      for (int e = lane; e < 256; e += 64)
        lXf[(a*16 + (e>>4))*65 + bb*16 + (e&15)] = 0.f;
    if (lane < 16) {
      const int cc = lane;
      for (int i=1; i<16; i++) {
        float s = 0.f;
        for (int j=0; j<i; j++) s += Lb[i*65+j] * Ub[j*65+cc];
        Ub[i*65+cc] = ((i==cc)?1.f:0.f) - s;
      }
    }
  }
  __syncthreads();

  bf16_t* lVT = lQV;   // [128][72]
  {
    const int m = t & 15;
    #pragma unroll
    for (int ib=0; ib<4; ib++) {
      int e0 = (t + 256*ib)*8;
      int r = e0 >> 7, cc = e0 & 127;
      bf16x8 v8 = *(const bf16x8*)(vg + e0);
      #pragma unroll
      for (int e=0;e<8;e++) {
        int ee = (e + m) & 7;
        lVT[(cc+ee)*72 + r] = v8[ee];
      }
    }
  }

  {
    const int i = t >> 4, j = t & 15;
    #pragma unroll
    for (int bb=0; bb<3; bb++) {
      float s = 0.f;
      const float* Mrow = lLf + ((bb+1)*16 + i)*65 + bb*16;
      const float* Ucol = lXf + (bb*16)*65 + bb*16 + j;
      #pragma unroll
      for (int k=0;k<16;k++) s += Mrow[k] * Ucol[k*65];
      lP[bb*272 + i*17 + j] = s;
    }
  }
  __syncthreads();
  {
    const int i = t >> 4, j = t & 15;
    #pragma unroll
    for (int bb=0; bb<3; bb++) {
      float s = 0.f;
      const float* Urow = lXf + ((bb+1)*16 + i)*65 + (bb+1)*16;
      const float* Pcol = lP + bb*272 + j;
      #pragma unroll
      for (int k=0;k<16;k++) s += Urow[k] * Pcol[k*17];
      lXf[((bb+1)*16 + i)*65 + bb*16 + j] = -s;
    }
  }
  __syncthreads();
  {
    const int i = t >> 4, j = t & 15;
    #pragma unroll
    for (int bb=0; bb<2; bb++) {
      float s = 0.f;
      const float* M0 = lLf + ((bb+2)*16 + i)*65 + bb*16;
      const float* U0 = lXf + (bb*16)*65 + bb*16 + j;
      const float* M1 = lLf + ((bb+2)*16 + i)*65 + (bb+1)*16;
      const float* T1 = lXf + ((bb+1)*16)*65 + bb*16 + j;
      #pragma unroll
      for (int k=0;k<16;k++) s += M0[k]*U0[k*65] + M1[k]*T1[k*65];
      lP[bb*272 + i*17 + j] = s;
    }
  }
  __syncthreads();
  {
    const int i = t >> 4, j = t & 15;
    #pragma unroll
    for (int bb=0; bb<2; bb++) {
      float s = 0.f;
      const float* Urow = lXf + ((bb+2)*16 + i)*65 + (bb+2)*16;
      const float* Pcol = lP + bb*272 + j;
      #pragma unroll
      for (int k=0;k<16;k++) s += Urow[k] * Pcol[k*17];
      lXf[((bb+2)*16 + i)*65 + bb*16 + j] = -s;
    }
  }
  __syncthreads();
  {
    const int i = t >> 4, j = t & 15;
    float s = 0.f;
    const float* M0 = lLf + (48 + i)*65 + 0;
    const float* U0 = lXf + 0*65 + j;
    const float* M1 = lLf + (48 + i)*65 + 16;
    const float* T1 = lXf + 16*65 + j;
    const float* M2 = lLf + (48 + i)*65 + 32;
    const float* T2 = lXf + 32*65 + j;
    #pragma unroll
    for (int k=0;k<16;k++) s += M0[k]*U0[k*65] + M1[k]*T1[k*65] + M2[k]*T2[k*65];
    lP[i*17 + j] = s;
  }
  __syncthreads();
  {
    const int i = t >> 4, j = t & 15;
    float s = 0.f;
    const float* Urow = lXf + (48 + i)*65 + 48;
    const float* Pcol = lP + j;
    #pragma unroll
    for (int k=0;k<16;k++) s += Urow[k] * Pcol[k*17];
    lXf[(48 + i)*65 + j] = -s;
  }
  __syncthreads();

  bf16_t* lXb = (bf16_t*)lLf;   // [64][72]
  {
    bf16_t* tpg = (bf16_t*)(cdp + CD_TP);
    #pragma unroll
    for (int ib=0; ib<16; ib++) {
      int idx = t + ib*256; int r = idx>>6, cc = idx&63;
      float xv = lXf[r*65+cc] * bvv[cc];
      tpg[r*64+cc] = (bf16_t)(xv * pvv[cc]);
      lXb[r*72+cc] = (bf16_t)xv;
    }
  }
  __syncthreads();

  {
    f32x4 acc[8];
    #pragma unroll
    for (int tn=0;tn<8;tn++) acc[tn]=(f32x4){0,0,0,0};
    #pragma unroll
    for (int ks=0;ks<2;ks++) {
      bf16x8 aX = *(const bf16x8*)&lXb[(w*16+fr)*72 + fq*8 + ks*32];
      #pragma unroll
      for (int tn=0;tn<8;tn++) {
        bf16x8 bV = *(const bf16x8*)&lVT[(tn*16+fr)*72 + fq*8 + ks*32];
        acc[tn] = MFMA16(aX, bV, acc[tn]);
      }
    }
    bf16_t* tvg = (bf16_t*)(cdp + CD_TV);
    #pragma unroll
    for (int tn=0;tn<8;tn++)
      #pragma unroll
      for (int r=0;r<4;r++) {
        int tt = w*16 + fq*4 + r, dv = tn*16 + fr;
        tvg[tt*128 + dv] = (bf16_t)acc[tn][r];
      }
  }

  {
    bf16_t* ktg = (bf16_t*)(cdp + CD_KTS);
    int dk = t >> 1, c0 = (t & 1)*32;
    bf16_t tmp[32];
    #pragma unroll
    for (int i2=0;i2<32;i2++) {
      int i = c0 + i2;
      tmp[i2] = (bf16_t)((float)lK[i*136 + dk] * evv[i]);
    }
    #pragma unroll
    for (int s8=0;s8<4;s8++)
      *(bf16x8*)&ktg[dk*64 + c0 + s8*8] = *(bf16x8*)&tmp[s8*8];
  }
  if (t < 64) ((float*)(cdp + CD_PV))[t] = pvv[t];
  if (t == 0) *((float*)(cdp + CD_PC)) = expf(gcv[63]);
}

// ---------------------------------------------------------------------------
// Phase S v3 (serial over 32 chunks; 256 blocks = 32 bh x 8 dv-splits):
//   double-buffered K/Q/Tp/KT staging; Aq read direct from global (L2-hot);
//   3 barriers/chunk; lS scale+update+bf16-convert folded into phase 3.
// LDS: lS@0 [16][129]f32, lSb@8320 [16][136], buf[2]@12672 (62464 each:
//   lK 17408 | lQ 17408 | lTp 9216 | lKT 18432), lXT@137600, lDT@140416.
// Total 143232 B (1 block/CU).
// ---------------------------------------------------------------------------
__global__ __launch_bounds__(256) void chunkS_kernel(
    const bf16_t* __restrict__ q_t, const bf16_t* __restrict__ k_t,
    const char* __restrict__ cdata, bf16_t* __restrict__ obuf)
{
  extern __shared__ char smem[];
  float*  lS  = (float*)(smem);              // [16][129]
  bf16_t* lSb = (bf16_t*)(smem + 8320);      // [16][136]
  bf16_t* lXT = (bf16_t*)(smem + 137600);    // [16][88]
  bf16_t* lDT = (bf16_t*)(smem + 140416);    // [16][88]

  const int bid = blockIdx.x;
  const int lb  = (bid & 7)*32 + (bid >> 3);
  const int bh = lb >> 3, sp = lb & 7;
  const int dv0 = sp*16;
  const int b = bh >> 4, h = bh & 15;
  const int t = threadIdx.x, lane = t & 63, w = t >> 6;
  const int fr = lane & 15, fq = lane >> 4;

  #pragma unroll
  for (int ib=0; ib<8; ib++) {
    int idx = t + ib*256; int r = idx>>7, cc = idx&127;
    lS[r*129+cc] = 0.f;
    lSb[r*136+cc] = (bf16_t)0.f;
  }

  const bf16_t* kg = k_t + (long)bh*SS*128;
  const bf16_t* qg = q_t + (long)bh*SS*128;

  bf16x8 kr0,kr1,kr2,kr3, qr0,qr1,qr2,qr3, kt0,kt1,kt2,kt3, tp0,tp1;

#define STAGE_LOAD(CSRC)                                                       \
  {                                                                            \
    const char* cdl = cdata + (long)(bh*NCH + (CSRC))*CD_STRIDE;               \
    const bf16_t* kl = kg + (long)(CSRC)*CH*128;                               \
    const bf16_t* ql = qg + (long)(CSRC)*CH*128;                               \
    const bf16_t* ktl = (const bf16_t*)(cdl + CD_KTS);                         \
    const bf16_t* tpl = (const bf16_t*)(cdl + CD_TP);                          \
    int e0 = t*8, e1 = (t+256)*8, e2 = (t+512)*8, e3 = (t+768)*8;              \
    kr0 = *(const bf16x8*)(kl + e0); kr1 = *(const bf16x8*)(kl + e1);          \
    kr2 = *(const bf16x8*)(kl + e2); kr3 = *(const bf16x8*)(kl + e3);          \
    qr0 = *(const bf16x8*)(ql + e0); qr1 = *(const bf16x8*)(ql + e1);          \
    qr2 = *(const bf16x8*)(ql + e2); qr3 = *(const bf16x8*)(ql + e3);          \
    kt0 = *(const bf16x8*)(ktl + e0); kt1 = *(const bf16x8*)(ktl + e1);        \
    kt2 = *(const bf16x8*)(ktl + e2); kt3 = *(const bf16x8*)(ktl + e3);        \
    tp0 = *(const bf16x8*)(tpl + e0); tp1 = *(const bf16x8*)(tpl + e1);        \
  }

#define STAGE_WRITE(BASE)                                                      \
  {                                                                            \
    char* _bp = (BASE);                                                        \
    bf16_t* _lK  = (bf16_t*)_bp;                                               \
    bf16_t* _lQ  = (bf16_t*)(_bp + 17408);                                     \
    bf16_t* _lTp = (bf16_t*)(_bp + 34816);                                     \
    bf16_t* _lKT = (bf16_t*)(_bp + 44032);                                     \
    int e0 = t*8, e1 = (t+256)*8, e2 = (t+512)*8, e3 = (t+768)*8;              \
    *(bf16x8*)&_lK[(e0>>7)*136 + (e0&127)] = kr0;                              \
    *(bf16x8*)&_lK[(e1>>7)*136 + (e1&127)] = kr1;                              \
    *(bf16x8*)&_lK[(e2>>7)*136 + (e2&127)] = kr2;                              \
    *(bf16x8*)&_lK[(e3>>7)*136 + (e3&127)] = kr3;                              \
    *(bf16x8*)&_lQ[(e0>>7)*136 + (e0&127)] = qr0;                              \
    *(bf16x8*)&_lQ[(e1>>7)*136 + (e1&127)] = qr1;                              \
    *(bf16x8*)&_lQ[(e2>>7)*136 + (e2&127)] = qr2;                              \
    *(bf16x8*)&_lQ[(e3>>7)*136 + (e3&127)] = qr3;                              \
    *(bf16x8*)&_lKT[(e0>>6)*72 + (e0&63)] = kt0;                               \
    *(bf16x8*)&_lKT[(e1>>6)*72 + (e1&63)] = kt1;                               \
    *(bf16x8*)&_lKT[(e2>>6)*72 + (e2&63)] = kt2;                               \
    *(bf16x8*)&_lKT[(e3>>6)*72 + (e3&63)] = kt3;                               \
    *(bf16x8*)&_lTp[(e0>>6)*72 + (e0&63)] = tp0;                               \
    *(bf16x8*)&_lTp[(e1>>6)*72 + (e1&63)] = tp1;                               \
  }

  STAGE_LOAD(0);
  STAGE_WRITE(smem + 12672);
  __syncthreads();

  for (int c=0; c<NCH; c++) {
    const int cd = bh*NCH + c;
    const char* cdp = cdata + (long)cd*CD_STRIDE;
    const int cb = c & 1;
    char* rbuf = smem + 12672 + cb*62464;
    bf16_t* lK  = (bf16_t*)rbuf;
    bf16_t* lQ  = (bf16_t*)(rbuf + 17408);
    bf16_t* lTp = (bf16_t*)(rbuf + 34816);
    bf16_t* lKT = (bf16_t*)(rbuf + 44032);

    float tvq0, tvq1, tvq2, tvq3, pc;
    float pvq[4];
    bf16x8 aqr0, aqr1;
    {
      const bf16_t* tvp = (const bf16_t*)(cdp + CD_TV);
      const float* pvp = (const float*)(cdp + CD_PV);
      const bf16_t* aqp = (const bf16_t*)(cdp + CD_AQ);
      tvq0 = (float)tvp[(w*16+fq*4+0)*128 + dv0 + fr];
      tvq1 = (float)tvp[(w*16+fq*4+1)*128 + dv0 + fr];
      tvq2 = (float)tvp[(w*16+fq*4+2)*128 + dv0 + fr];
      tvq3 = (float)tvp[(w*16+fq*4+3)*128 + dv0 + fr];
      #pragma unroll
      for (int r=0;r<4;r++) pvq[r] = pvp[w*16+fq*4+r];
      pc = *(const float*)(cdp + CD_PC);
      aqr0 = *(const bf16x8*)(aqp + (w*16+fr)*64 + fq*8);
      aqr1 = *(const bf16x8*)(aqp + (w*16+fr)*64 + fq*8 + 32);
    }
    const int cn = (c+1 < NCH) ? c+1 : c;
    STAGE_LOAD(cn);

    // phase 1: X = K S^T-slice, Xq = Q S^T-slice
    f32x4 aX = {0,0,0,0}, aXq = {0,0,0,0};
    #pragma unroll
    for (int ks=0; ks<4; ks++) {
      bf16x8 bS = *(const bf16x8*)&lSb[fr*136 + fq*8 + ks*32];
      bf16x8 aK = *(const bf16x8*)&lK[(w*16+fr)*136 + fq*8 + ks*32];
      bf16x8 aQ = *(const bf16x8*)&lQ[(w*16+fr)*136 + fq*8 + ks*32];
      aX  = MFMA16(aK, bS, aX);
      aXq = MFMA16(aQ, bS, aXq);
    }
    #pragma unroll
    for (int r=0;r<4;r++)
      lXT[fr*88 + (w*16+fq*4+r)] = (bf16_t)aX[r];
    __syncthreads();   // A

    // phase 2: D = TV - Tp X
    {
      f32x4 aD = {0,0,0,0};
      #pragma unroll
      for (int ks=0; ks<2; ks++) {
        bf16x8 aT = *(const bf16x8*)&lTp[(w*16+fr)*72 + fq*8 + ks*32];
        bf16x8 bX = *(const bf16x8*)&lXT[fr*88 + fq*8 + ks*32];
        aD = MFMA16(aT, bX, aD);
      }
      lDT[fr*88 + (w*16+fq*4+0)] = (bf16_t)(tvq0 - aD[0]);
      lDT[fr*88 + (w*16+fq*4+1)] = (bf16_t)(tvq1 - aD[1]);
      lDT[fr*88 + (w*16+fq*4+2)] = (bf16_t)(tvq2 - aD[2]);
      lDT[fr*88 + (w*16+fq*4+3)] = (bf16_t)(tvq3 - aD[3]);
    }
    __syncthreads();   // B

    // write next chunk's staging into the other buffer (drains under phase 3)
    STAGE_WRITE(smem + 12672 + (cb^1)*62464);

    // phase 3: S = pc*S + D^T KTs^T (fold + inline bf16); O written directly
    {
      f32x4 aS0 = {0,0,0,0}, aS1 = {0,0,0,0}, aO = {0,0,0,0};
      #pragma unroll
      for (int ks=0; ks<2; ks++) {
        bf16x8 aDd = *(const bf16x8*)&lDT[fr*88 + fq*8 + ks*32];
        bf16x8 bK0 = *(const bf16x8*)&lKT[(w*32+fr)*72 + fq*8 + ks*32];
        bf16x8 bK1 = *(const bf16x8*)&lKT[(w*32+16+fr)*72 + fq*8 + ks*32];
        bf16x8 aA  = (ks==0) ? aqr0 : aqr1;
        bf16x8 bD  = *(const bf16x8*)&lDT[fr*88 + fq*8 + ks*32];
        aS0 = MFMA16(aDd, bK0, aS0);
        aS1 = MFMA16(aDd, bK1, aS1);
        aO  = MFMA16(aA,  bD,  aO);
      }
      #pragma unroll
      for (int r=0;r<4;r++) {
        int dvr = fq*4 + r;
        float s0 = lS[dvr*129 + w*32 + fr]      * pc + aS0[r];
        float s1 = lS[dvr*129 + w*32 + 16 + fr] * pc + aS1[r];
        lS[dvr*129 + w*32 + fr]      = s0;
        lS[dvr*129 + w*32 + 16 + fr] = s1;
        lSb[dvr*136 + w*32 + fr]      = (bf16_t)s0;
        lSb[dvr*136 + w*32 + 16 + fr] = (bf16_t)s1;
      }
      #pragma unroll
      for (int r=0;r<4;r++) {
        int tt = w*16+fq*4+r;
        long tok = (long)b*SS + c*CH + tt;
        float ov = pvq[r]*aXq[r] + aO[r];
        obuf[(tok*HH + h)*128 + dv0 + fr] = (bf16_t)ov;
      }
    }
    __syncthreads();   // C
  }
#undef STAGE_LOAD
#undef STAGE_WRITE
}

// ---------------------------------------------------------------------------
// RMSNorm over DV + (1+nw) + silu(z) gate; wave-per-row, no LDS/barrier.
// ---------------------------------------------------------------------------
__global__ __launch_bounds__(256) void norm_gate_kernel(
    const bf16_t* __restrict__ o, const bf16_t* __restrict__ zfull,
    const float* __restrict__ nw, bf16_t* __restrict__ og)
{
  const long row = (long)blockIdx.x*4 + (threadIdx.x >> 6);  // (b*S+s)*H + h
  const int lane = threadIdx.x & 63;
  const long tok = row >> 4;
  const int h = row & 15;
  bf16x2 xv = *(const bf16x2*)(o + row*128 + lane*2);
  float x0 = (float)xv[0], x1 = (float)xv[1];
  float ss = x0*x0 + x1*x1;
  #pragma unroll
  for (int off=32; off>=1; off>>=1) ss += __shfl_xor(ss, off);
  float rr = rsqrtf(ss*(1.f/128.f) + 1e-6f);
  bf16x2 zv = *(const bf16x2*)(zfull + tok*DD + h*128 + lane*2);
  float z0 = (float)zv[0], z1 = (float)zv[1];
  float v0 = x0 * rr * (1.f + nw[lane*2])   * (z0 * (1.f/(1.f+expf(-z0))));
  float v1 = x1 * rr * (1.f + nw[lane*2+1]) * (z1 * (1.f/(1.f+expf(-z1))));
  bf16x2 ov; ov[0] = (bf16_t)v0; ov[1] = (bf16_t)v1;
  *(bf16x2*)(og + row*128 + lane*2) = ov;
}

// ---------------------------------------------------------------------------
extern "C" void kernel_launch(void* const* d_in, const int* in_sizes, int n_in,
                              void* d_out, int out_size, void* d_ws, size_t ws_size,
                              hipStream_t stream)
{
  const float* hs    = (const float*)d_in[0];
  const float* amask = (const float*)d_in[1];
  const float* Wqkv  = (const float*)d_in[2];
  const float* convw = (const float*)d_in[3];
  const float* convb = (const float*)d_in[4];
  const float* Wz    = (const float*)d_in[5];
  const float* Wb    = (const float*)d_in[6];
  const float* Wa    = (const float*)d_in[7];
  const float* dtb   = (const float*)d_in[8];
  const float* Alog  = (const float*)d_in[9];
  const float* nw    = (const float*)d_in[10];
  const float* Wout  = (const float*)d_in[11];

  const size_t MB = 1024*1024;
  char* p = (char*)d_ws;
  auto alloc = [&](size_t bytes) { char* r = p; p += (bytes + 255) & ~(size_t)255; return r; };
  bf16_t* x_bf   = (bf16_t*)alloc(16*MB);   // x_bf
  char*   bigreg = alloc(84*MB);            // wB@0 (32MB), mixed@34MB (48MB); later cdata@0
  bf16_t* wba    = (bf16_t*)alloc(256*1024);// [32][2048] bf16
  bf16_t* woutb  = (bf16_t*)alloc(8*MB);    // Wout bf16
  bf16_t* zbuf   = (bf16_t*)alloc(16*MB);   // [4096][2048]
  bf16_t* q_t    = (bf16_t*)alloc(16*MB);   // q; later og
  bf16_t* k_t    = (bf16_t*)alloc(16*MB);
  bf16_t* v_t    = (bf16_t*)alloc(16*MB);   // v; later obuf
  float2* gb_t   = (float2*)alloc((size_t)BB*HH*SS*8);
  size_t need = (size_t)(p - (char*)d_ws);
  if (ws_size < need) return;   // clean fail (absmax = poison)

  bf16_t* wB      = (bf16_t*)bigreg;              // [8192][2048] bf16
  bf16_t* mixed   = (bf16_t*)(bigreg + 34*MB);    // [4096][6144] bf16
  char*   cdata   = bigreg;                       // after fused GEMM + conv consumed
  bf16_t* obuf    = v_t;                          // after chunkA consumed v_t
  bf16_t* og      = q_t;                          // after chunkS consumed q_t

  cast_all_kernel<<<2048, 256, 0, stream>>>(hs, amask, Wqkv, Wz, Wb, Wa, Wout,
                                            x_bf, wB, wba, woutb);

  betag3_kernel<<<MM/16, 256, 0, stream>>>(x_bf, wba, dtb, Alog, gb_t);

  gemm_fused<<<512, 512, 131072, stream>>>(x_bf, wB, mixed, zbuf, DD, 32);

  conv_norm_kernel<<<BB*HH*(SS/32), 256, 0, stream>>>(mixed, convw, convb, q_t, k_t, v_t);

  chunkA_kernel<<<BB*HH*NCH, 256, 73408, stream>>>(q_t, k_t, v_t, gb_t, cdata);
  chunkS_kernel<<<BB*HH*8, 256, 143232, stream>>>(q_t, k_t, cdata, obuf);

  norm_gate_kernel<<<MM*HH/4, 256, 0, stream>>>(obuf, zbuf, nw, og);

  gemm256<false><<<256, 512, 98304, stream>>>(og, woutb, d_out, MM, DD, DD, 16);
}